// Round 3
// baseline (187.908 us; speedup 1.0000x reference)
//
#include <hip/hip_runtime.h>

#define C_DIM 128
#define HW_DIM 6144

typedef __attribute__((ext_vector_type(8))) short short8;
typedef __attribute__((ext_vector_type(4))) float f32x4;

static __device__ __forceinline__ unsigned short f2bf(float x) {
    unsigned int u = __builtin_bit_cast(unsigned int, x);
    u = (u + 0x7FFFu + ((u >> 16) & 1u)) >> 16;
    return (unsigned short)u;
}
static __device__ __forceinline__ float bf2f(unsigned short u) {
    unsigned int x = ((unsigned int)u) << 16;
    return __builtin_bit_cast(float, x);
}
static __device__ __forceinline__ unsigned int pack2(float a, float b) {
    return (unsigned int)f2bf(a) | ((unsigned int)f2bf(b) << 16);
}
static __device__ __forceinline__ f32x4 mfma_bf16(short8 a, short8 b, f32x4 c) {
    return __builtin_amdgcn_mfma_f32_16x16x32_bf16(a, b, c, 0, 0, 0);
}
// async global->LDS, 16B per lane; LDS dest is wave-uniform-base + lane*16,
// global source is per-lane (pre-swizzled).
static __device__ __forceinline__ void gload16(const unsigned short* g,
                                               unsigned short* l) {
    __builtin_amdgcn_global_load_lds(
        (const __attribute__((address_space(1))) unsigned int*)g,
        (__attribute__((address_space(3))) unsigned int*)l, 16, 0, 0);
}
// Load one MFMA A-fragment (bf16) directly from global fp32 W[o][c]:
// lane (l16,quad) of row-tile base `o` needs W[o][c0 .. c0+7], c0=s*32+quad*8.
static __device__ __forceinline__ short8 wfrag(const float* Wrow) {
    float4 a = *(const float4*)Wrow;
    float4 b = *(const float4*)(Wrow + 4);
    unsigned int u[4] = {pack2(a.x, a.y), pack2(a.z, a.w),
                         pack2(b.x, b.y), pack2(b.z, b.w)};
    return *(const short8*)u;
}

// ---------------------------------------------------------------------------
// r17 conv kernel: fused (1x1 conv -> BN -> LReLU) x nconv, M=128, N=64, K=128.
//  - W fragments loaded DIRECTLY from global fp32 (L2-hot, 64 KB/weight) into
//    registers — no W LDS staging. LDS drops 64.25 -> 32.3 KB = 4 blocks/CU.
//  - nconv=2: conv1 result (BN+LReLU, bf16) goes to Ct in the Xt B-operand
//    swizzle; conv2 reads it as its B tile. Kills the old Qmid/Kmid global
//    round-trip and the whole second launch.
// in_mode : 0 = X fp32 [b][c][hw] (transpose-stage)
//           1 = X bf16 [b][pos][c] (direct stage)
//           2 = combine: sum of nparts partials [pos][c] bf16 * invL[pos]
// out_mode: 0 = bf16 [b][pos][c] * oscale
//           1 = bf16 [b][c][pos]
//           2 = fp32 [b][c][hw] + residual
// ---------------------------------------------------------------------------
struct MJob {
    const void* X;          // input (or P-partials base for in_mode 2)
    const float* L;         // L-partials base (in_mode 2)
    const float* W1; const float* G1; const float* B1;
    const float* W2; const float* G2; const float* B2;
    void* out; const float* resid;
    float oscale; int in_mode; int out_mode; int nparts; int nconv;
};
struct MJobs { MJob j[3]; };

__global__ __launch_bounds__(256)
void conv_mfma(MJobs jobs)
{
    const MJob jb = (blockIdx.z == 0) ? jobs.j[0]
                  : (blockIdx.z == 1) ? jobs.j[1] : jobs.j[2];

    __shared__ __align__(16) unsigned short Xt[64 * 128];   // 16 KB conv1 B
    __shared__ __align__(16) unsigned short Ct[64 * 128];   // 16 KB mid / epi
    __shared__ float invl[64];

    const int t    = threadIdx.x;
    const int b    = blockIdx.y;
    const int p0   = blockIdx.x * 64;
    const int wave = t >> 6;
    const int lane = t & 63;
    const int quad = lane >> 4;
    const int l16  = lane & 15;

    // ---- W fragments direct from global (rows o = (wave*2+mi)*16+l16) ----
    short8 af1[2][4], af2[2][4];
#pragma unroll
    for (int mi = 0; mi < 2; ++mi) {
        int o = (wave * 2 + mi) * 16 + l16;
#pragma unroll
        for (int s = 0; s < 4; ++s)
            af1[mi][s] = wfrag(jb.W1 + o * C_DIM + s * 32 + quad * 8);
    }
    if (jb.nconv == 2) {
#pragma unroll
        for (int mi = 0; mi < 2; ++mi) {
            int o = (wave * 2 + mi) * 16 + l16;
#pragma unroll
            for (int s = 0; s < 4; ++s)
                af2[mi][s] = wfrag(jb.W2 + o * C_DIM + s * 32 + quad * 8);
        }
    }

    // ---- stage X per in_mode -> bf16 Xt[p][chunk^(p&15)] ----
    if (jb.in_mode == 0) {
        const float* Xg = (const float*)jb.X + (size_t)b * C_DIM * HW_DIM;
#pragma unroll
        for (int i = 0; i < 8; ++i) {
            int f = i * 1024 + t * 4;         // c = f>>6, p = f&63 (mult of 4)
            int c = f >> 6, p = f & 63;
            float4 x4 = *(const float4*)&Xg[(size_t)c * HW_DIM + p0 + p];
            float xv[4] = {x4.x, x4.y, x4.z, x4.w};
#pragma unroll
            for (int j = 0; j < 4; ++j) {
                int pp = p + j;
                Xt[pp * 128 + (((c >> 3) ^ (pp & 15)) * 8) + (c & 7)] = f2bf(xv[j]);
            }
        }
    } else if (jb.in_mode == 1) {
        const unsigned short* Xg = (const unsigned short*)jb.X;
#pragma unroll
        for (int i = 0; i < 4; ++i) {
            int idx = t + 256 * i;            // p = idx>>4, ch = idx&15
            int p = idx >> 4, ch = idx & 15;
            uint4 v = *(const uint4*)&Xg[((size_t)b * HW_DIM + p0 + p) * C_DIM + ch * 8];
            *(uint4*)&Xt[p * 128 + ((ch ^ (p & 15)) * 8)] = v;
        }
    } else {
        if (t < 64) {
            size_t li = (size_t)b * HW_DIM + p0 + t;
            float s = 0.f;
            for (int pr = 0; pr < jb.nparts; ++pr)
                s += jb.L[li + (size_t)pr * (2 * HW_DIM)];
            invl[t] = 1.0f / s;
        }
        __syncthreads();
        const unsigned short* A0 = (const unsigned short*)jb.X;
        const size_t pstride = (size_t)2 * HW_DIM * C_DIM;   // ushorts per part
#pragma unroll
        for (int i = 0; i < 4; ++i) {
            int idx = t + 256 * i;
            int p = idx >> 4, ch = idx & 15;
            size_t gi = ((size_t)b * HW_DIM + p0 + p) * C_DIM + ch * 8;
            float acc8[8] = {0.f, 0.f, 0.f, 0.f, 0.f, 0.f, 0.f, 0.f};
            for (int pr = 0; pr < jb.nparts; ++pr) {
                uint4 a = *(const uint4*)&A0[gi + (size_t)pr * pstride];
                const unsigned int* ap = (const unsigned int*)&a;
#pragma unroll
                for (int j = 0; j < 4; ++j) {
                    acc8[2 * j]     += bf2f((unsigned short)(ap[j] & 0xFFFF));
                    acc8[2 * j + 1] += bf2f((unsigned short)(ap[j] >> 16));
                }
            }
            float s = invl[p];
            unsigned int w[4];
#pragma unroll
            for (int j = 0; j < 4; ++j)
                w[j] = pack2(acc8[2 * j] * s, acc8[2 * j + 1] * s);
            *(uint4*)&Xt[p * 128 + ((ch ^ (p & 15)) * 8)] = *(uint4*)w;
        }
    }
    __syncthreads();

    const float BNRS = 0.99999500003749972f;  // 1/sqrt(1 + 1e-5)

    // ---- conv1 GEMM: wave does m-tiles {2w,2w+1} x 4 n-tiles, K=128 ----
    f32x4 acc[2][4];
#pragma unroll
    for (int mi = 0; mi < 2; ++mi)
#pragma unroll
        for (int nt = 0; nt < 4; ++nt) acc[mi][nt] = (f32x4){0.f, 0.f, 0.f, 0.f};
#pragma unroll
    for (int nt = 0; nt < 4; ++nt)
#pragma unroll
        for (int s = 0; s < 4; ++s) {
            short8 bf = *(const short8*)
                &Xt[(nt * 16 + l16) * 128 + (((4 * s + quad) ^ l16) * 8)];
            acc[0][nt] = mfma_bf16(af1[0][s], bf, acc[0][nt]);
            acc[1][nt] = mfma_bf16(af1[1][s], bf, acc[1][nt]);
        }

    // ---- BN1 + LeakyReLU ----
#pragma unroll
    for (int mi = 0; mi < 2; ++mi)
#pragma unroll
        for (int r = 0; r < 4; ++r) {
            int o = (wave * 2 + mi) * 16 + quad * 4 + r;
            float sc = jb.G1[o] * BNRS, bb = jb.B1[o];
#pragma unroll
            for (int nt = 0; nt < 4; ++nt) {
                float y = fmaf(acc[mi][nt][r], sc, bb);
                acc[mi][nt][r] = y > 0.f ? y : 0.1f * y;
            }
        }

    if (jb.nconv == 2) {
        // ---- mid -> Ct in B-operand swizzle (bf16: same rounding as the old
        //      Qmid/Kmid global round-trip) ----
#pragma unroll
        for (int mi = 0; mi < 2; ++mi)
#pragma unroll
            for (int nt = 0; nt < 4; ++nt)
#pragma unroll
                for (int r = 0; r < 4; ++r) {
                    int o = (wave * 2 + mi) * 16 + quad * 4 + r;
                    int p = nt * 16 + l16;
                    Ct[p * 128 + (((o >> 3) ^ (p & 15)) * 8) + (o & 7)] =
                        f2bf(acc[mi][nt][r]);
                }
        __syncthreads();

        // ---- conv2 GEMM from Ct ----
#pragma unroll
        for (int mi = 0; mi < 2; ++mi)
#pragma unroll
            for (int nt = 0; nt < 4; ++nt) acc[mi][nt] = (f32x4){0.f, 0.f, 0.f, 0.f};
#pragma unroll
        for (int nt = 0; nt < 4; ++nt)
#pragma unroll
            for (int s = 0; s < 4; ++s) {
                short8 bf = *(const short8*)
                    &Ct[(nt * 16 + l16) * 128 + (((4 * s + quad) ^ l16) * 8)];
                acc[0][nt] = mfma_bf16(af2[0][s], bf, acc[0][nt]);
                acc[1][nt] = mfma_bf16(af2[1][s], bf, acc[1][nt]);
            }

        // ---- BN2 + LeakyReLU ----
#pragma unroll
        for (int mi = 0; mi < 2; ++mi)
#pragma unroll
            for (int r = 0; r < 4; ++r) {
                int o = (wave * 2 + mi) * 16 + quad * 4 + r;
                float sc = jb.G2[o] * BNRS, bb = jb.B2[o];
#pragma unroll
                for (int nt = 0; nt < 4; ++nt) {
                    float y = fmaf(acc[mi][nt][r], sc, bb);
                    acc[mi][nt][r] = y > 0.f ? y : 0.1f * y;
                }
            }
    }

    // ---- epilogue ----
    // Staging buffer: Xt is dead after conv1 reads (fused path syncs before
    // reuse); Ct is free in the single-conv path.
    unsigned short* EP = (jb.nconv == 2) ? Xt : Ct;
    if (jb.out_mode == 0) {
        unsigned short* O = (unsigned short*)jb.out;
        float os = jb.oscale;
        if (jb.nconv != 2) __syncthreads();   // fused path already synced
#pragma unroll
        for (int mi = 0; mi < 2; ++mi)
#pragma unroll
            for (int nt = 0; nt < 4; ++nt)
#pragma unroll
                for (int r = 0; r < 4; ++r) {
                    int o = (wave * 2 + mi) * 16 + quad * 4 + r;
                    int p = nt * 16 + l16;
                    EP[p * 128 + (((o >> 3) ^ (p & 15)) * 8) + (o & 7)] =
                        f2bf(acc[mi][nt][r] * os);
                }
        __syncthreads();
#pragma unroll
        for (int i = 0; i < 4; ++i) {
            int idx = t + 256 * i;
            int p = idx >> 4, ch = idx & 15;
            uint4 v = *(const uint4*)&EP[p * 128 + ((ch ^ (p & 15)) * 8)];
            *(uint4*)&O[((size_t)b * HW_DIM + p0 + p) * C_DIM + ch * 8] = v;
        }
    } else if (jb.out_mode == 1) {
        unsigned short* O = (unsigned short*)jb.out;
        if (jb.nconv != 2) __syncthreads();
#pragma unroll
        for (int mi = 0; mi < 2; ++mi)
#pragma unroll
            for (int nt = 0; nt < 4; ++nt)
#pragma unroll
                for (int r = 0; r < 4; ++r) {
                    int o = (wave * 2 + mi) * 16 + quad * 4 + r;
                    int p = nt * 16 + l16;
                    EP[o * 64 + (((p >> 3) ^ (o & 7)) * 8) + (p & 7)] =
                        f2bf(acc[mi][nt][r]);
                }
        __syncthreads();
#pragma unroll
        for (int i = 0; i < 4; ++i) {          // all 1024 chunks
            int idx = t + 256 * i;
            int o = idx >> 3, ch = idx & 7;
            uint4 v = *(const uint4*)&EP[o * 64 + ((ch ^ (o & 7)) * 8)];
            *(uint4*)&O[((size_t)b * C_DIM + o) * HW_DIM + p0 + ch * 8] = v;
        }
    } else {
        float* O = (float*)jb.out;
#pragma unroll
        for (int mi = 0; mi < 2; ++mi)
#pragma unroll
            for (int nt = 0; nt < 4; ++nt)
#pragma unroll
                for (int r = 0; r < 4; ++r) {
                    int o = (wave * 2 + mi) * 16 + quad * 4 + r;
                    size_t g = ((size_t)b * C_DIM + o) * HW_DIM + p0 + nt * 16 + l16;
                    O[g] = acc[mi][nt][r] + jb.resid[g];
                }
    }
}

// ---------------------------------------------------------------------------
// Flash attention (r16, UNCHANGED — proven 59 µs / passing).
// ---------------------------------------------------------------------------
template <int NSPLIT>
__global__ __launch_bounds__(256, 3)
void flash_attn(const unsigned short* __restrict__ Q,
                const unsigned short* __restrict__ K,
                const unsigned short* __restrict__ V,
                unsigned short* __restrict__ Pbase,
                float* __restrict__ Lbase)
{
    __shared__ __align__(16) unsigned short Kt[64 * 128];     // 16 KB
    __shared__ __align__(16) unsigned short Vt[128 * 64];     // 16 KB
    __shared__ __align__(16) unsigned short Plds[4][16][64];  // 8 KB swizzled

    const int t    = threadIdx.x;
    const int wave = t >> 6;
    const int lane = t & 63;
    const int quad = lane >> 4;
    const int l16  = lane & 15;

    constexpr int KS_BITS = (NSPLIT == 8) ? 3 : 2;
    const int bid  = blockIdx.x;
    const int ks   = bid & (NSPLIT - 1);        // = XCD under round-robin
    const int b    = (bid >> KS_BITS) & 1;
    const int qblk = bid >> (KS_BITS + 1);      // 0..47
    const int q0   = qblk * 128 + wave * 32;
    const int kbeg = ks * (HW_DIM / NSPLIT);

    unsigned short* __restrict__ Po = Pbase + (size_t)ks * (2 * HW_DIM * C_DIM);
    float* __restrict__ Lo          = Lbase + (size_t)ks * (2 * HW_DIM);

    const unsigned short* Qb = Q + (size_t)b * HW_DIM * C_DIM;
    const unsigned short* Kb = K + (size_t)b * HW_DIM * C_DIM;
    const unsigned short* Vb = V + (size_t)b * C_DIM * HW_DIM;

    // Q fragments: 2 row-tiles x K=128
    short8 qf[2][4];
#pragma unroll
    for (int rt = 0; rt < 2; ++rt)
#pragma unroll
        for (int s = 0; s < 4; ++s)
            qf[rt][s] = *(const short8*)
                &Qb[(size_t)(q0 + rt * 16 + l16) * C_DIM + s * 32 + quad * 8];

    f32x4 O[2][8];
#pragma unroll
    for (int rt = 0; rt < 2; ++rt)
#pragma unroll
        for (int h = 0; h < 8; ++h) O[rt][h] = (f32x4){0.f, 0.f, 0.f, 0.f};
    float lsum[2][4] = {{0, 0, 0, 0}, {0, 0, 0, 0}};

    // Precomputed swizzled source offsets (ushort units) for staging.
    int koff[4], voff[4];
#pragma unroll
    for (int j = 0; j < 4; ++j) {
        int ci = t + 256 * j;
        int kr = ci >> 4, kc = ci & 15;
        koff[j] = kr * C_DIM + ((kc ^ (kr & 15)) << 3);
        int vr = ci >> 3, vc = ci & 7;
        voff[j] = vr * HW_DIM + ((vc ^ (vr & 7)) << 3);
    }

    const int NIT = (HW_DIM / NSPLIT) / 64;     // 12 (NSPLIT=8) / 24 (=4)
    for (int it = 0; it < NIT; ++it) {
        const int kb = kbeg + it * 64;
        const unsigned short* Ksrc = Kb + (size_t)kb * C_DIM;
        const unsigned short* Vsrc = Vb + kb;
#pragma unroll
        for (int j = 0; j < 4; ++j) {
            int ci = t + 256 * j;
            gload16(Ksrc + koff[j], &Kt[ci * 8]);
            gload16(Vsrc + voff[j], &Vt[ci * 8]);
        }
        __syncthreads();   // drains vmcnt(0): tiles landed; prev reads done

        // ---- QK^T: S[rt][n] over 64 k-cols, K=128 ----
        f32x4 S[2][4];
#pragma unroll
        for (int rt = 0; rt < 2; ++rt)
#pragma unroll
            for (int n = 0; n < 4; ++n) S[rt][n] = (f32x4){0.f, 0.f, 0.f, 0.f};
#pragma unroll
        for (int n = 0; n < 4; ++n)
#pragma unroll
            for (int s = 0; s < 4; ++s) {
                short8 kf = *(const short8*)
                    &Kt[(size_t)(n * 16 + l16) * 128 + (((4 * s + quad) ^ l16) * 8)];
                S[0][n] = mfma_bf16(qf[0][s], kf, S[0][n]);
                S[1][n] = mfma_bf16(qf[1][s], kf, S[1][n]);
            }

        // ---- exp2 -> Plds (swizzled) -> pa fragments ----
        short8 pa[2][2];
#pragma unroll
        for (int rt = 0; rt < 2; ++rt) {
#pragma unroll
            for (int n = 0; n < 4; ++n)
#pragma unroll
                for (int r = 0; r < 4; ++r) {
                    float e = __builtin_amdgcn_exp2f(S[rt][n][r]);
                    lsum[rt][r] += e;
                    int row = quad * 4 + r;
                    Plds[wave][row][(((n * 2 + (l16 >> 3)) ^ (row & 7)) << 3) | (l16 & 7)] =
                        f2bf(e);
                }
            pa[rt][0] = *(const short8*)&Plds[wave][l16][((quad       ^ (l16 & 7)) << 3)];
            pa[rt][1] = *(const short8*)&Plds[wave][l16][(((4 + quad) ^ (l16 & 7)) << 3)];
        }

        // ---- PV ----
        const int m = l16 & 7;
#pragma unroll
        for (int h = 0; h < 8; ++h) {
            short8 v0 = *(const short8*)&Vt[(size_t)(h * 16 + l16) * 64 + ((quad ^ m) * 8)];
            short8 v1 = *(const short8*)&Vt[(size_t)(h * 16 + l16) * 64 + (((quad + 4) ^ m) * 8)];
            O[0][h] = mfma_bf16(pa[0][0], v0, O[0][h]);
            O[0][h] = mfma_bf16(pa[0][1], v1, O[0][h]);
            O[1][h] = mfma_bf16(pa[1][0], v0, O[1][h]);
            O[1][h] = mfma_bf16(pa[1][1], v1, O[1][h]);
        }
        __syncthreads();   // all waves done reading before next overwrite
    }

    // ---- row-sum reduce across 16 cols ----
#pragma unroll
    for (int off = 1; off < 16; off <<= 1)
#pragma unroll
        for (int rt = 0; rt < 2; ++rt)
#pragma unroll
            for (int r = 0; r < 4; ++r)
                lsum[rt][r] += __shfl_xor(lsum[rt][r], off, 64);

    // ---- write P partial + L partial ----
#pragma unroll
    for (int rt = 0; rt < 2; ++rt)
#pragma unroll
        for (int r = 0; r < 4; ++r) {
            int lrow = wave * 32 + rt * 16 + quad * 4 + r;
            size_t row = (size_t)b * HW_DIM + qblk * 128 + lrow;
            if (l16 == 0) Lo[row] = lsum[rt][r];
#pragma unroll
            for (int h = 0; h < 8; ++h)
                Po[row * C_DIM + h * 16 + l16] = f2bf(O[rt][h][r]);
        }
}

// ---------------------------------------------------------------------------
extern "C" void kernel_launch(void* const* d_in, const int* in_sizes, int n_in,
                              void* d_out, int out_size, void* d_ws, size_t ws_size,
                              hipStream_t stream)
{
    const float* query = (const float*)d_in[0];
    const float* key   = (const float*)d_in[1];
    const float* q_w1 = (const float*)d_in[2];
    const float* q_g1 = (const float*)d_in[3];
    const float* q_b1 = (const float*)d_in[4];
    const float* q_w2 = (const float*)d_in[5];
    const float* q_g2 = (const float*)d_in[6];
    const float* q_b2 = (const float*)d_in[7];
    const float* k_w1 = (const float*)d_in[8];
    const float* k_g1 = (const float*)d_in[9];
    const float* k_b1 = (const float*)d_in[10];
    const float* k_w2 = (const float*)d_in[11];
    const float* k_g2 = (const float*)d_in[12];
    const float* k_b2 = (const float*)d_in[13];
    const float* v_w  = (const float*)d_in[14];
    const float* v_g  = (const float*)d_in[15];
    const float* v_b  = (const float*)d_in[16];
    const float* o_w  = (const float*)d_in[17];
    const float* o_g  = (const float*)d_in[18];
    const float* o_b  = (const float*)d_in[19];

    // Workspace layout (contiguous):
    //   [ P partials: nsplit x 3145728 B ][ Qbf ][ Kbf ][ Vbf ][ L: nsplit x 49152 B ]
    // nsplit=8 needs 34,996,224 B (proven available); nsplit=4 needs
    // 22,216,704 B. (No Qmid/Kmid anymore — convs are fused.)
    const size_t PPART = (size_t)2 * HW_DIM * C_DIM * 2;  // 3,145,728 B
    const size_t LPART = (size_t)2 * HW_DIM * 4;          // 49,152 B
    const int nsplit = (ws_size >= 11 * PPART + 8 * LPART) ? 8 : 4;

    char* ws = (char*)d_ws;
    unsigned short* Pbase = (unsigned short*)ws;
    unsigned short* Qbf = (unsigned short*)(ws + (size_t)nsplit * PPART);
    unsigned short* Kbf = (unsigned short*)(ws + (size_t)nsplit * PPART + PPART);
    unsigned short* Vbf = (unsigned short*)(ws + (size_t)nsplit * PPART + 2 * PPART);
    float*          Lbase = (float*)(ws + (size_t)nsplit * PPART + 3 * PPART);
    float* outp = (float*)d_out;

    const float qscale = 0.08838834764831845f * 1.44269504088896340f;

    // Launch A: fused double-convs. z0: query->conv1->conv2->Qbf (scaled);
    // z1: key->conv1->conv2->Kbf; z2: key->v-conv->Vbf.
    {
        MJobs J{};
        J.j[0] = {query, nullptr, q_w1, q_g1, q_b1, q_w2, q_g2, q_b2,
                  (void*)Qbf, nullptr, qscale, 0, 0, 0, 2};
        J.j[1] = {key,   nullptr, k_w1, k_g1, k_b1, k_w2, k_g2, k_b2,
                  (void*)Kbf, nullptr, 1.0f,   0, 0, 0, 2};
        J.j[2] = {key,   nullptr, v_w,  v_g,  v_b,  nullptr, nullptr, nullptr,
                  (void*)Vbf, nullptr, 1.0f,   0, 1, 0, 1};
        hipLaunchKernelGGL(conv_mfma, dim3(HW_DIM / 64, 2, 3), dim3(256),
                           0, stream, J);
    }

    // Flash: 4-wave blocks, 128 q-rows each, NSPLIT-way k-split.
    if (nsplit == 8) {
        hipLaunchKernelGGL(HIP_KERNEL_NAME(flash_attn<8>),
                           dim3(2 * (HW_DIM / 128) * 8), dim3(256),
                           0, stream, Qbf, Kbf, Vbf, Pbase, Lbase);
    } else {
        hipLaunchKernelGGL(HIP_KERNEL_NAME(flash_attn<4>),
                           dim3(2 * (HW_DIM / 128) * 4), dim3(256),
                           0, stream, Qbf, Kbf, Vbf, Pbase, Lbase);
    }

    // Launch C: combine nsplit partials -> out-conv + residual.
    {
        MJobs J{};
        J.j[0] = {Pbase, Lbase, o_w, o_g, o_b, nullptr, nullptr, nullptr,
                  (void*)outp, query, 1.0f, 2, 2, nsplit, 1};
        J.j[1] = J.j[0];
        J.j[2] = J.j[0];
        hipLaunchKernelGGL(conv_mfma, dim3(HW_DIM / 64, 2, 1), dim3(256),
                           0, stream, J);
    }
}